// Round 1
// baseline (515.744 us; speedup 1.0000x reference)
//
#include <hip/hip_runtime.h>
#include <hip/hip_bf16.h>

typedef __attribute__((ext_vector_type(8))) __bf16 bf16x8;
typedef __attribute__((ext_vector_type(4))) float f32x4;
typedef unsigned short u16;

#define TOK 8192          // B*N rows
#define C_DIM 1024
#define OUT_SEC 8388608   // elements per output section (x, q, k, v, hidden)

__device__ __forceinline__ u16 f2bf(float f) {
  return __builtin_bit_cast(u16, __float2bfloat16(f));
}

__device__ __forceinline__ void gl_lds16(const void* g, void* l) {
  __builtin_amdgcn_global_load_lds(
      (__attribute__((address_space(1))) void*)const_cast<void*>(g),
      (__attribute__((address_space(3))) void*)l, 16, 0, 0);
}

// ---------------- fp32 -> bf16 weight conversion ----------------
__global__ __launch_bounds__(256) void cvt_kernel(const float* __restrict__ in,
                                                  u16* __restrict__ out, int n4) {
  int i = blockIdx.x * blockDim.x + threadIdx.x;
  if (i >= n4) return;
  float4 v = reinterpret_cast<const float4*>(in)[i];
  alignas(8) u16 pk[4];
  pk[0] = f2bf(v.x); pk[1] = f2bf(v.y); pk[2] = f2bf(v.z); pk[3] = f2bf(v.w);
  reinterpret_cast<uint2*>(out)[i] = *reinterpret_cast<uint2*>(pk);
}

// ---------------- LayerNorm (one block per row of 1024) ----------------
__global__ __launch_bounds__(256) void ln_kernel(const float* __restrict__ x,
                                                 const float* __restrict__ w,
                                                 const float* __restrict__ b,
                                                 u16* __restrict__ out) {
  const int row = blockIdx.x;
  const int t = threadIdx.x;
  const float* xr = x + (size_t)row * C_DIM;
  float4 v = reinterpret_cast<const float4*>(xr)[t];
  float s = v.x + v.y + v.z + v.w;
  float ss = v.x * v.x + v.y * v.y + v.z * v.z + v.w * v.w;
#pragma unroll
  for (int off = 1; off < 64; off <<= 1) {
    s += __shfl_xor(s, off, 64);
    ss += __shfl_xor(ss, off, 64);
  }
  __shared__ float red[8];
  const int wv = t >> 6;
  if ((t & 63) == 0) { red[wv] = s; red[4 + wv] = ss; }
  __syncthreads();
  s = red[0] + red[1] + red[2] + red[3];
  ss = red[4] + red[5] + red[6] + red[7];
  const float mu = s * (1.0f / C_DIM);
  const float var = ss * (1.0f / C_DIM) - mu * mu;
  const float rstd = rsqrtf(var + 1e-5f);
  float4 w4 = reinterpret_cast<const float4*>(w)[t];
  float4 b4 = reinterpret_cast<const float4*>(b)[t];
  alignas(8) u16 pk[4];
  pk[0] = f2bf((v.x - mu) * rstd * w4.x + b4.x);
  pk[1] = f2bf((v.y - mu) * rstd * w4.y + b4.y);
  pk[2] = f2bf((v.z - mu) * rstd * w4.z + b4.z);
  pk[3] = f2bf((v.w - mu) * rstd * w4.w + b4.w);
  reinterpret_cast<uint2*>(out + (size_t)row * C_DIM)[t] = *reinterpret_cast<uint2*>(pk);
}

// ---------------- GEMM: C[M,N] = A[M,K](bf16) * B[N,K](bf16)^T ----------------
// m97 structure: 128x128 tile, BK=32, 4 waves (2x2 of 64x64), global_load_lds w=16.
enum { EPI_QKV = 0, EPI_PROJ = 1, EPI_FC1 = 2, EPI_FC2 = 3 };

template <int EPI>
__global__ __launch_bounds__(256) void gemm_bt(
    const u16* __restrict__ A, const u16* __restrict__ Bw,
    const float* __restrict__ bias, const float* __restrict__ resid,
    float* __restrict__ out, float* __restrict__ out2_f,
    u16* __restrict__ out2_h, int M, int N, int K) {
  __shared__ u16 As[128 * 32];
  __shared__ u16 Bs[128 * 32];
  const int t = threadIdx.x;
  const int lane = t & 63;
  const int wv = t >> 6;
  const int wr = wv >> 1, wc = wv & 1;
  const int row0 = blockIdx.x * 128, col0 = blockIdx.y * 128;

  f32x4 zero = {0.f, 0.f, 0.f, 0.f};
  f32x4 acc[4][4];
#pragma unroll
  for (int m = 0; m < 4; ++m)
#pragma unroll
    for (int n = 0; n < 4; ++n) acc[m][n] = zero;

  // staging: thread t covers tile row t/4 (issue 0) / 64 + t/4 (issue 1), cols (t%4)*8..+8
  const int srow = t >> 2;
  const int scol = (t & 3) * 8;
  const u16* ga0 = A + (size_t)(row0 + srow) * K + scol;
  const u16* ga1 = A + (size_t)(row0 + 64 + srow) * K + scol;
  const u16* gb0 = Bw + (size_t)(col0 + srow) * K + scol;
  const u16* gb1 = Bw + (size_t)(col0 + 64 + srow) * K + scol;

  for (int k0 = 0; k0 < K; k0 += 32) {
    __syncthreads();
    gl_lds16(ga0 + k0, As + t * 8);
    gl_lds16(ga1 + k0, As + 2048 + t * 8);
    gl_lds16(gb0 + k0, Bs + t * 8);
    gl_lds16(gb1 + k0, Bs + 2048 + t * 8);
    __syncthreads();
    bf16x8 af[4], bfr[4];
#pragma unroll
    for (int m = 0; m < 4; ++m)
      af[m] = *reinterpret_cast<const bf16x8*>(
          As + (wr * 64 + m * 16 + (lane & 15)) * 32 + (lane >> 4) * 8);
#pragma unroll
    for (int n = 0; n < 4; ++n)
      bfr[n] = *reinterpret_cast<const bf16x8*>(
          Bs + (wc * 64 + n * 16 + (lane & 15)) * 32 + (lane >> 4) * 8);
#pragma unroll
    for (int m = 0; m < 4; ++m)
#pragma unroll
      for (int n = 0; n < 4; ++n)
        acc[m][n] = __builtin_amdgcn_mfma_f32_16x16x32_bf16(af[m], bfr[n], acc[m][n], 0, 0, 0);
  }

  const int rb = row0 + wr * 64;
  const int cb = col0 + wc * 64;
#pragma unroll
  for (int m = 0; m < 4; ++m) {
#pragma unroll
    for (int n = 0; n < 4; ++n) {
      const int c = cb + n * 16 + (lane & 15);
#pragma unroll
      for (int j = 0; j < 4; ++j) {
        const int r = rb + m * 16 + (lane >> 4) * 4 + j;
        float v = acc[m][n][j];
        if constexpr (EPI == EPI_QKV) {
          const int sec = c >> 10, cc = c & 1023;
          out[(size_t)sec * OUT_SEC + (size_t)r * 1024 + cc] = v;
        } else if constexpr (EPI == EPI_PROJ) {
          v += bias[c] + resid[(size_t)r * 1024 + c];
          out[(size_t)r * 1024 + c] = v;
        } else if constexpr (EPI == EPI_FC1) {
          v += bias[c];
          const float g = 0.5f * v * (1.0f + erff(v * 0.70710678118f));
          out2_h[(size_t)r * 4096 + c] = f2bf(g);
        } else {  // EPI_FC2
          v += bias[c];
          out[(size_t)r * 1024 + c] = v;  // hidden_out
          out2_f[(size_t)r * 1024 + c] = resid[(size_t)r * 1024 + c] + v;  // final x
        }
      }
    }
  }
}

// ---------------- Flash attention ----------------
// grid: (B*H=128, N/64=16). 4 waves; wave owns 16 Q rows. KV tiles of 64.
// q/k/v read fp32 from d_out sections; scale 1/8 folded into Q at bf16 convert.
__global__ __launch_bounds__(256) void attn_kernel(const float* __restrict__ qkv_out,
                                                   u16* __restrict__ ao) {
  const int bh = blockIdx.x;
  const int qt = blockIdx.y;
  const int b = bh >> 4, h = bh & 15;
  const int t = threadIdx.x, lane = t & 63, wv = t >> 6;
  const size_t base = (size_t)b * 1024 * 1024 + h * 64;
  const float* Qg = qkv_out + base;
  const float* Kg = qkv_out + (size_t)OUT_SEC + base;
  const float* Vg = qkv_out + 2 * (size_t)OUT_SEC + base;

  __shared__ u16 Ks[64][72];   // row = kv, col = d   (pad 72: bank-conflict fix)
  __shared__ u16 Vt[64][72];   // row = d,  col = kv
  __shared__ u16 Ps[4][16][72];

  const int q0 = qt * 64 + wv * 16;
  bf16x8 qf[2];
#pragma unroll
  for (int c = 0; c < 2; ++c) {
    const float* p = Qg + (size_t)(q0 + (lane & 15)) * 1024 + c * 32 + (lane >> 4) * 8;
    float4 u0 = reinterpret_cast<const float4*>(p)[0];
    float4 u1 = reinterpret_cast<const float4*>(p)[1];
    alignas(16) u16 tmp[8];
    tmp[0] = f2bf(u0.x * 0.125f); tmp[1] = f2bf(u0.y * 0.125f);
    tmp[2] = f2bf(u0.z * 0.125f); tmp[3] = f2bf(u0.w * 0.125f);
    tmp[4] = f2bf(u1.x * 0.125f); tmp[5] = f2bf(u1.y * 0.125f);
    tmp[6] = f2bf(u1.z * 0.125f); tmp[7] = f2bf(u1.w * 0.125f);
    qf[c] = *reinterpret_cast<bf16x8*>(tmp);
  }

  f32x4 zero = {0.f, 0.f, 0.f, 0.f};
  f32x4 accO[4];
#pragma unroll
  for (int nb = 0; nb < 4; ++nb) accO[nb] = zero;
  float mrun[4], lrun[4];
#pragma unroll
  for (int j = 0; j < 4; ++j) { mrun[j] = -1e30f; lrun[j] = 0.f; }

  for (int kv0 = 0; kv0 < 1024; kv0 += 64) {
    __syncthreads();
    {  // stage K (row-major) and V (transposed); thread t: row r=t/4, d0=(t%4)*16
      const int r = t >> 2, d0 = (t & 3) * 16;
      const float* kp = Kg + (size_t)(kv0 + r) * 1024 + d0;
      const float* vp = Vg + (size_t)(kv0 + r) * 1024 + d0;
      float4 k4[4], v4[4];
#pragma unroll
      for (int i = 0; i < 4; ++i) {
        k4[i] = reinterpret_cast<const float4*>(kp)[i];
        v4[i] = reinterpret_cast<const float4*>(vp)[i];
      }
      alignas(16) u16 kb[16];
#pragma unroll
      for (int i = 0; i < 4; ++i) {
        kb[i * 4 + 0] = f2bf(k4[i].x); kb[i * 4 + 1] = f2bf(k4[i].y);
        kb[i * 4 + 2] = f2bf(k4[i].z); kb[i * 4 + 3] = f2bf(k4[i].w);
      }
      *reinterpret_cast<bf16x8*>(&Ks[r][d0]) = *reinterpret_cast<bf16x8*>(kb);
      *reinterpret_cast<bf16x8*>(&Ks[r][d0 + 8]) = *reinterpret_cast<bf16x8*>(kb + 8);
#pragma unroll
      for (int i = 0; i < 4; ++i) {
        Vt[d0 + i * 4 + 0][r] = f2bf(v4[i].x);
        Vt[d0 + i * 4 + 1][r] = f2bf(v4[i].y);
        Vt[d0 + i * 4 + 2][r] = f2bf(v4[i].z);
        Vt[d0 + i * 4 + 3][r] = f2bf(v4[i].w);
      }
    }
    __syncthreads();

    // S = (Q/8) K^T : 4 col-blocks of 16 kv
    f32x4 sacc[4];
#pragma unroll
    for (int jb = 0; jb < 4; ++jb) sacc[jb] = zero;
#pragma unroll
    for (int jb = 0; jb < 4; ++jb)
#pragma unroll
      for (int c = 0; c < 2; ++c) {
        bf16x8 kf = *reinterpret_cast<const bf16x8*>(
            &Ks[jb * 16 + (lane & 15)][c * 32 + (lane >> 4) * 8]);
        sacc[jb] = __builtin_amdgcn_mfma_f32_16x16x32_bf16(qf[c], kf, sacc[jb], 0, 0, 0);
      }

    // online softmax; row j's 16 lanes share group (lane>>4)
    float pv[4][4];
#pragma unroll
    for (int j = 0; j < 4; ++j) {
      float mt = fmaxf(fmaxf(sacc[0][j], sacc[1][j]), fmaxf(sacc[2][j], sacc[3][j]));
#pragma unroll
      for (int off = 1; off < 16; off <<= 1) mt = fmaxf(mt, __shfl_xor(mt, off, 64));
      const float mn = fmaxf(mrun[j], mt);
      const float sc = __expf(mrun[j] - mn);
      float rs = 0.f;
#pragma unroll
      for (int jb = 0; jb < 4; ++jb) {
        const float p = __expf(sacc[jb][j] - mn);
        pv[jb][j] = p;
        rs += p;
      }
#pragma unroll
      for (int off = 1; off < 16; off <<= 1) rs += __shfl_xor(rs, off, 64);
      lrun[j] = lrun[j] * sc + rs;
      mrun[j] = mn;
#pragma unroll
      for (int nb = 0; nb < 4; ++nb) accO[nb][j] *= sc;
    }

    // P: C-frag layout -> LDS -> A-frag layout
#pragma unroll
    for (int j = 0; j < 4; ++j)
#pragma unroll
      for (int jb = 0; jb < 4; ++jb)
        Ps[wv][(lane >> 4) * 4 + j][jb * 16 + (lane & 15)] = f2bf(pv[jb][j]);
    __syncthreads();
    bf16x8 pf[2];
#pragma unroll
    for (int c = 0; c < 2; ++c)
      pf[c] = *reinterpret_cast<const bf16x8*>(
          &Ps[wv][lane & 15][c * 32 + (lane >> 4) * 8]);

    // O += P V
#pragma unroll
    for (int nb = 0; nb < 4; ++nb)
#pragma unroll
      for (int c = 0; c < 2; ++c) {
        bf16x8 vf = *reinterpret_cast<const bf16x8*>(
            &Vt[nb * 16 + (lane & 15)][c * 32 + (lane >> 4) * 8]);
        accO[nb] = __builtin_amdgcn_mfma_f32_16x16x32_bf16(pf[c], vf, accO[nb], 0, 0, 0);
      }
  }

#pragma unroll
  for (int nb = 0; nb < 4; ++nb)
#pragma unroll
    for (int j = 0; j < 4; ++j) {
      const int r = q0 + (lane >> 4) * 4 + j;
      const int d = nb * 16 + (lane & 15);
      const float o = accO[nb][j] / lrun[j];
      ao[(size_t)(b * 1024 + r) * 1024 + h * 64 + d] = f2bf(o);
    }
}

// ---------------- launch ----------------
extern "C" void kernel_launch(void* const* d_in, const int* in_sizes, int n_in,
                              void* d_out, int out_size, void* d_ws, size_t ws_size,
                              hipStream_t stream) {
  const float* x      = (const float*)d_in[0];
  const float* n1w    = (const float*)d_in[1];
  const float* n1b    = (const float*)d_in[2];
  const float* qkv_w  = (const float*)d_in[3];
  const float* proj_w = (const float*)d_in[4];
  const float* proj_b = (const float*)d_in[5];
  const float* n2w    = (const float*)d_in[6];
  const float* n2b    = (const float*)d_in[7];
  const float* fc1_w  = (const float*)d_in[8];
  const float* fc1_b  = (const float*)d_in[9];
  const float* fc2_w  = (const float*)d_in[10];
  const float* fc2_b  = (const float*)d_in[11];
  float* out = (float*)d_out;

  // workspace layout (u16 elements)
  u16* wsb    = (u16*)d_ws;
  u16* w_qkv  = wsb;               // 3072*1024
  u16* w_proj = wsb + 3145728;     // 1024*1024
  u16* w_fc1  = wsb + 4194304;     // 4096*1024
  u16* w_fc2  = wsb + 8388608;     // 1024*4096
  u16* xn     = wsb + 12582912;    // 8192*1024 (reused for xn2)
  u16* ao     = wsb + 20971520;    // 8192*1024; h buffer aliases here (8192*4096)
  u16* hbuf   = ao;

  cvt_kernel<<<3072, 256, 0, stream>>>(qkv_w, w_qkv, 786432);
  cvt_kernel<<<1024, 256, 0, stream>>>(proj_w, w_proj, 262144);
  cvt_kernel<<<4096, 256, 0, stream>>>(fc1_w, w_fc1, 1048576);
  cvt_kernel<<<4096, 256, 0, stream>>>(fc2_w, w_fc2, 1048576);

  // xn = LN(x)
  ln_kernel<<<TOK, 256, 0, stream>>>(x, n1w, n1b, xn);
  // q,k,v fp32 -> d_out sections 1..3
  gemm_bt<EPI_QKV><<<dim3(64, 24), 256, 0, stream>>>(
      xn, w_qkv, nullptr, nullptr, out + OUT_SEC, nullptr, nullptr, TOK, 3072, 1024);
  // attention -> ao (bf16)
  attn_kernel<<<dim3(128, 16), 256, 0, stream>>>(out + OUT_SEC, ao);
  // x_mid = x + ao*proj^T + proj_b -> d_out[0:8M]
  gemm_bt<EPI_PROJ><<<dim3(64, 8), 256, 0, stream>>>(
      ao, w_proj, proj_b, x, out, nullptr, nullptr, TOK, 1024, 1024);
  // xn2 = LN(x_mid)
  ln_kernel<<<TOK, 256, 0, stream>>>(out, n2w, n2b, xn);
  // h = gelu(xn2*fc1^T + fc1_b) (bf16, overwrites ao region)
  gemm_bt<EPI_FC1><<<dim3(64, 32), 256, 0, stream>>>(
      xn, w_fc1, fc1_b, nullptr, nullptr, nullptr, hbuf, TOK, 4096, 1024);
  // hidden = h*fc2^T + fc2_b -> d_out sec4 ; final x = x_mid + hidden -> d_out sec0
  gemm_bt<EPI_FC2><<<dim3(64, 8), 256, 0, stream>>>(
      hbuf, w_fc2, fc2_b, out, out + 4 * (size_t)OUT_SEC, out, nullptr, TOK, 1024, 4096);
}